// Round 16
// baseline (44.064 us; speedup 1.0000x reference)
//
#include <hip/hip_runtime.h>
#include <math.h>

namespace {

constexpr int IMG  = 128;
constexpr int NPIX = IMG * IMG;
constexpr int B    = 4;
constexpr int V    = 600;
constexpr int F    = 1000;
constexpr float FOCALF = 1.5f;
constexpr float EPSF   = 1e-8f;
// affine-filter margins (error bounds >= 4x slack; round-15-proven):
constexpr float EW   = 1e-4f;       // |g~ - g_ref| <= ~2.5e-5
constexpr float EBIN = 2e-4f;       // corner-eval slack for bin test
constexpr float DENSAFE = 1e-3f;    // below this -> eps=INF (always exact)

struct FaceRec {
    float e0x, e0y, bx, by;
    float e1x, e1y, cx, cy;
    float e2x, e2y, ax, ay;
    float den, z0, z1, z2;
};

// Exact reference projection + edge setup (identical rounding in all users).
__device__ inline FaceRec project_face(const float* __restrict__ vb,
                                       const int* __restrict__ faces, int f) {
#pragma clang fp contract(off)
    FaceRec r;
    int i0 = faces[f * 3 + 0], i1 = faces[f * 3 + 1], i2 = faces[f * 3 + 2];
    float x0 = vb[i0 * 3], y0 = vb[i0 * 3 + 1]; r.z0 = vb[i0 * 3 + 2];
    float x1 = vb[i1 * 3], y1 = vb[i1 * 3 + 1]; r.z1 = vb[i1 * 3 + 2];
    float x2 = vb[i2 * 3], y2 = vb[i2 * 3 + 1]; r.z2 = vb[i2 * 3 + 2];
    r.ax = (FOCALF * x0) / r.z0; r.ay = (FOCALF * y0) / r.z0;
    r.bx = (FOCALF * x1) / r.z1; r.by = (FOCALF * y1) / r.z1;
    r.cx = (FOCALF * x2) / r.z2; r.cy = (FOCALF * y2) / r.z2;
    r.e0x = r.cx - r.bx; r.e0y = r.cy - r.by;
    r.e1x = r.ax - r.cx; r.e1y = r.ay - r.cy;
    r.e2x = r.bx - r.ax; r.e2y = r.by - r.ay;
    float den = r.e2x * (r.cy - r.ay) - r.e2y * (r.cx - r.ax); // == ref area
    if (!(fabsf(den) > EPSF)) den = 0.0f;
    r.den = den;
    return r;
}

__device__ inline float seg_dist2(float px, float py, float ax, float ay,
                                  float bx, float by) {
#pragma clang fp contract(off)
    float ex = bx - ax, ey = by - ay;
    float dx = px - ax, dy = py - ay;
    float ee = fmaxf(ex * ex + ey * ey, EPSF);
    float t  = (dx * ex + dy * ey) / ee;
    t = fminf(fmaxf(t, 0.0f), 1.0f);
    float rx = dx - t * ex;
    float ry = dy - t * ey;
    return rx * rx + ry * ry;
}

// Fused setup+bin+shade. 512 blocks x 256 thr (4 waves).
// Block = (b 2b, chgrp 3b, tilegrp 4b): 128 faces (2 chunks) x 8 tiles of
// 8x16 px (stratified 2x4 lattice, ticket-balanced across the 4 waves).
// Each lane owns 2 pixels (rows iy, iy+8) -> per-face loop costs amortize.
// In-block setup builds the 7-float4 records in LDS with reference rounding.
// Cheap affine filter + z~ window -> exact IEEE path only when a lane might
// improve its bound; all skips strict-loss-proven; order-free u64-min merge.
__global__ __launch_bounds__(256, 8) void rast(const float* __restrict__ verts,
                                               const int* __restrict__ faces,
                                               unsigned long long* __restrict__ zbest) {
#pragma clang fp contract(off)
    __shared__ float4 sface[128 * 7];    // 14 KB
    __shared__ unsigned int lticket;
    const int tid  = threadIdx.x;
    const int lane = tid & 63;
    const int bk   = blockIdx.x;
    const int b     = bk & 3;
    const int chgrp = (bk >> 2) & 7;     // 128-face group
    const int tg    = bk >> 5;           // 0..15 tile-group
    if (tid == 0) lticket = 0u;

    // ---- in-block setup: build 128 face records in LDS ----
    if (tid < 128) {
        const int fid = chgrp * 128 + tid;
        float4 o0, o1, o2, o3, o4, o5, o6;
        bool dead = (fid >= F);
        FaceRec r = {};
        if (!dead) {
            r = project_face(verts + (size_t)b * V * 3, faces, fid);
            dead = (r.den == 0.0f);
        }
        if (dead) {
            o0 = make_float4(0.0f, 0.0f, -1e30f, 0.0f);
            o1 = make_float4(0.0f, 0.0f, -1e30f, 0.0f);
            o2 = make_float4(0.0f, 0.0f, 0.0f, 0.0f);
            o3 = o4 = o5 = o6 = make_float4(0.0f, 0.0f, 0.0f, 0.0f);
        } else {
            // affine edge coeffs: w_i = a_i*px + b_i*py + c_i
            float a0 = -r.e0y, b0 = r.e0x, c0 = r.e0y * r.bx - r.e0x * r.by;
            float a1 = -r.e1y, b1 = r.e1x, c1 = r.e1y * r.cx - r.e1x * r.cy;
            float a2 = -r.e2y, b2 = r.e2x, c2 = r.e2y * r.ax - r.e2x * r.ay;
            const float s  = r.den > 0.0f ? 1.0f : -1.0f;
            const float rd = __builtin_amdgcn_rcpf(r.den);
            const float azr = r.z0 * rd, bzr = r.z1 * rd, czr = r.z2 * rd;
            const float Zx = a0 * azr + a1 * bzr + a2 * czr;
            const float Zy = b0 * azr + b1 * bzr + b2 * czr;
            const float Zc = c0 * azr + c1 * bzr + c2 * czr;
            const float S = (fabsf(a0) + fabsf(b0) + fabsf(c0)) * fabsf(azr)
                          + (fabsf(a1) + fabsf(b1) + fabsf(c1)) * fabsf(bzr)
                          + (fabsf(a2) + fabsf(b2) + fabsf(c2)) * fabsf(czr);
            const float eps = (fabsf(r.den) < DENSAFE) ? INFINITY
                                                       : (1e-4f + 2e-6f * S);
            o0 = make_float4(s * a0, s * b0, s * c0, s * r.den);  // sden=|den|
            o1 = make_float4(s * a1, s * b1, s * c1, eps);
            o2 = make_float4(Zx, Zy, Zc, 0.0f);
            o3 = make_float4(r.e0x, r.e0y, r.bx, r.by);
            o4 = make_float4(r.e1x, r.e1y, r.cx, r.cy);
            o5 = make_float4(r.e2x, r.e2y, r.ax, r.ay);
            o6 = make_float4(r.den, r.z0, r.z1, r.z2);
        }
        float4* o = &sface[tid * 7];
        o[0] = o0; o[1] = o1; o[2] = o2; o[3] = o3; o[4] = o4; o[5] = o5; o[6] = o6;
    }
    __syncthreads();

    // pin per-lane bin coeffs for both chunks
    float4 mm0[2], mm1[2];
    mm0[0] = sface[lane * 7 + 0];        mm1[0] = sface[lane * 7 + 1];
    mm0[1] = sface[(64 + lane) * 7 + 0]; mm1[1] = sface[(64 + lane) * 7 + 1];

    const int r0g = tg >> 2, c0g = tg & 3;   // tile-group lattice phase
    const int dpx = lane & 7, dpy = lane >> 3;

    for (;;) {
        unsigned int j = 0;
        if (lane == 0) j = atomicAdd(&lticket, 1u);
        j = (unsigned int)__shfl((int)j, 0);
        if (j >= 8u) break;
        const unsigned int jj = (j + (unsigned int)chgrp) & 7u;   // stagger

        const int row = r0g + 4 * (int)(jj >> 2);   // 0..7 (16-px rows)
        const int col = c0g + 4 * (int)(jj & 3);    // 0..15 (8-px cols)
        const int ix0 = col * 8, iy0 = row * 16;
        const int ix  = ix0 + dpx;
        const int iyA = iy0 + dpy, iyB = iyA + 8;
        const float px  = 1.0f - (2.0f * (float)ix  + 1.0f) / (float)IMG;
        const float pyA = 1.0f - (2.0f * (float)iyA + 1.0f) / (float)IMG;
        const float pyB = 1.0f - (2.0f * (float)iyB + 1.0f) / (float)IMG;
        const float pxmax = 1.0f - (2.0f * (float)ix0 + 1.0f) / (float)IMG;
        const float pxmin = 1.0f - (2.0f * (float)(ix0 + 7) + 1.0f) / (float)IMG;
        const float pymax = 1.0f - (2.0f * (float)iy0 + 1.0f) / (float)IMG;
        const float pymin = 1.0f - (2.0f * (float)(iy0 + 15) + 1.0f) / (float)IMG;

        const int gpA = b * NPIX + iyA * IMG + ix;
        const int gpB = gpA + 8 * IMG;
        const unsigned ztopA = (unsigned)(zbest[gpA] >> 32);
        const unsigned ztopB = (unsigned)(zbest[gpB] >> 32);
        float zA = (ztopA == 0xFFFFFFFFu) ? INFINITY : __uint_as_float(ztopA);
        float zB = (ztopB == 0xFFFFFFFFu) ? INFINITY : __uint_as_float(ztopB);

        unsigned long long pminA = ~0ULL, pminB = ~0ULL;

        #pragma unroll
        for (int k = 0; k < 2; ++k) {
            const float4 m0 = mm0[k], m1 = mm1[k];
            const float a2s = -(m0.x + m1.x);
            const float b2s = -(m0.y + m1.y);
            const float c2s = m0.w - m0.z - m1.z;
            // bin test: max over 8x16 rect of each affine edge >= -EBIN
            bool pass =
                (m0.x * (m0.x >= 0.0f ? pxmax : pxmin)
               + m0.y * (m0.y >= 0.0f ? pymax : pymin) + m0.z) >= -EBIN;
            pass &=
                (m1.x * (m1.x >= 0.0f ? pxmax : pxmin)
               + m1.y * (m1.y >= 0.0f ? pymax : pymin) + m1.z) >= -EBIN;
            pass &=
                (a2s * (a2s >= 0.0f ? pxmax : pxmin)
               + b2s * (b2s >= 0.0f ? pymax : pymin) + c2s) >= -EBIN;

            unsigned long long mask = __ballot(pass);
            const int base = k * 64;
            while (mask) {
                const int sl = __builtin_ctzll(mask);
                mask &= mask - 1;
                const float4 k0 = sface[(base + sl) * 7 + 0];
                const float4 k1 = sface[(base + sl) * 7 + 1];
                // cheap affine inside test, both pixels
                const float g0A = fmaf(k0.x, px, fmaf(k0.y, pyA, k0.z));
                const float g1A = fmaf(k1.x, px, fmaf(k1.y, pyA, k1.z));
                const float g2A = k0.w - g0A - g1A;
                const float g0B = fmaf(k0.x, px, fmaf(k0.y, pyB, k0.z));
                const float g1B = fmaf(k1.x, px, fmaf(k1.y, pyB, k1.z));
                const float g2B = k0.w - g0B - g1B;
                const bool mayA = (g0A >= -EW) & (g1A >= -EW) & (g2A >= -EW);
                const bool mayB = (g0B >= -EW) & (g1B >= -EW) & (g2B >= -EW);
                if (!__any(mayA | mayB)) continue;
                const float4 kz = sface[(base + sl) * 7 + 2];
                const float ztA = fmaf(kz.x, px, fmaf(kz.y, pyA, kz.z));
                const float ztB = fmaf(kz.x, px, fmaf(kz.y, pyB, kz.z));
                const bool needA = mayA & (ztA < zA + k1.w);   // k1.w = eps
                const bool needB = mayB & (ztB < zB + k1.w);
                if (__any(needA)) {
                    // ---- bit-exact reference path, pixel A ----
                    const float4 r0 = sface[(base + sl) * 7 + 3];
                    const float4 r1 = sface[(base + sl) * 7 + 4];
                    const float4 r2 = sface[(base + sl) * 7 + 5];
                    const float4 r3 = sface[(base + sl) * 7 + 6];
                    const float den = r3.x;
                    float w0 = r0.x * (pyA - r0.w) - r0.y * (px - r0.z);
                    float w1 = r1.x * (pyA - r1.w) - r1.y * (px - r1.z);
                    float w2 = r2.x * (pyA - r2.w) - r2.y * (px - r2.z);
                    const unsigned ds = __float_as_uint(den) >> 31;
                    const bool in0 = (w0 == 0.0f) | ((__float_as_uint(w0) >> 31) == ds);
                    const bool in1 = (w1 == 0.0f) | ((__float_as_uint(w1) >> 31) == ds);
                    const bool in2 = (w2 == 0.0f) | ((__float_as_uint(w2) >> 31) == ds);
                    if (in0 & in1 & in2) {
                        float s0 = w0 / den, s1 = w1 / den, s2 = w2 / den;
                        float z  = s0 * r3.y + s1 * r3.z + s2 * r3.w;
                        if (z > 0.0f) {
                            unsigned long long pk =
                                ((unsigned long long)__float_as_uint(z) << 32) |
                                (unsigned)(chgrp * 128 + base + sl);
                            pminA = pminA < pk ? pminA : pk;
                            zA = fminf(zA, z);
                        }
                    }
                }
                if (__any(needB)) {
                    // ---- bit-exact reference path, pixel B ----
                    const float4 r0 = sface[(base + sl) * 7 + 3];
                    const float4 r1 = sface[(base + sl) * 7 + 4];
                    const float4 r2 = sface[(base + sl) * 7 + 5];
                    const float4 r3 = sface[(base + sl) * 7 + 6];
                    const float den = r3.x;
                    float w0 = r0.x * (pyB - r0.w) - r0.y * (px - r0.z);
                    float w1 = r1.x * (pyB - r1.w) - r1.y * (px - r1.z);
                    float w2 = r2.x * (pyB - r2.w) - r2.y * (px - r2.z);
                    const unsigned ds = __float_as_uint(den) >> 31;
                    const bool in0 = (w0 == 0.0f) | ((__float_as_uint(w0) >> 31) == ds);
                    const bool in1 = (w1 == 0.0f) | ((__float_as_uint(w1) >> 31) == ds);
                    const bool in2 = (w2 == 0.0f) | ((__float_as_uint(w2) >> 31) == ds);
                    if (in0 & in1 & in2) {
                        float s0 = w0 / den, s1 = w1 / den, s2 = w2 / den;
                        float z  = s0 * r3.y + s1 * r3.z + s2 * r3.w;
                        if (z > 0.0f) {
                            unsigned long long pk =
                                ((unsigned long long)__float_as_uint(z) << 32) |
                                (unsigned)(chgrp * 128 + base + sl);
                            pminB = pminB < pk ? pminB : pk;
                            zB = fminf(zB, z);
                        }
                    }
                }
            }
        }
        if (pminA != ~0ULL) atomicMin(&zbest[gpA], pminA);
        if (pminB != ~0ULL) atomicMin(&zbest[gpB], pminB);
    }
}

// Unpack winner; recompute bary + dists from verts/faces with the exact
// reference formulas (bit-identical to the winning candidate's arithmetic).
__global__ __launch_bounds__(256) void pass2(const float* __restrict__ verts,
                                             const int* __restrict__ faces,
                                             const unsigned long long* __restrict__ zbest,
                                             float* __restrict__ out) {
#pragma clang fp contract(off)
    const int gp = blockIdx.x * 256 + threadIdx.x;
    const int b  = gp >> 14;
    const int p  = gp & (NPIX - 1);
    const int ix = p & (IMG - 1), iy = p >> 7;

    unsigned long long packed = zbest[gp];
    float o_face = -1.0f, o_z = -1.0f, o_b0 = -1.0f, o_b1 = -1.0f,
          o_b2 = -1.0f, o_d = -1.0f;

    if (packed != ~0ULL) {
        const int   idx = (int)(unsigned)(packed & 0xffffffffu);
        const float z   = __uint_as_float((unsigned)(packed >> 32));
        const float px  = 1.0f - (2.0f * (float)ix + 1.0f) / (float)IMG;
        const float py  = 1.0f - (2.0f * (float)iy + 1.0f) / (float)IMG;

        FaceRec r = project_face(verts + (size_t)b * V * 3, faces, idx);
        float w0 = r.e0x * (py - r.by) - r.e0y * (px - r.bx);
        float w1 = r.e1x * (py - r.cy) - r.e1y * (px - r.cx);
        float w2 = r.e2x * (py - r.ay) - r.e2y * (px - r.ax);
        float s0 = w0 / r.den, s1 = w1 / r.den, s2 = w2 / r.den;

        float d2 = fminf(fminf(seg_dist2(px, py, r.ax, r.ay, r.bx, r.by),
                               seg_dist2(px, py, r.bx, r.by, r.cx, r.cy)),
                         seg_dist2(px, py, r.cx, r.cy, r.ax, r.ay));
        o_face = (float)idx; o_z = z;
        o_b0 = s0; o_b1 = s1; o_b2 = s2;
        o_d = -d2;
    }

    out[gp]            = o_face;
    out[B * NPIX + gp] = o_z;
    const int bary_base = 2 * B * NPIX;
    out[bary_base + gp * 3 + 0] = o_b0;
    out[bary_base + gp * 3 + 1] = o_b1;
    out[bary_base + gp * 3 + 2] = o_b2;
    out[5 * B * NPIX + gp] = o_d;
}

} // namespace

extern "C" void kernel_launch(void* const* d_in, const int* in_sizes, int n_in,
                              void* d_out, int out_size, void* d_ws, size_t ws_size,
                              hipStream_t stream) {
    const float* verts = (const float*)d_in[0];  // (B,V,3) f32
    const int*   faces = (const int*)d_in[1];    // (F,3) i32
    float* out = (float*)d_out;

    unsigned long long* zbest = (unsigned long long*)d_ws;   // 512 KB

    hipMemsetAsync(zbest, 0xFF, (size_t)B * NPIX * 8, stream);
    // 512 blocks x 4 waves; block = (image, 128-face group, 8-tile lattice
    // group); 8 blocks/CU = 32 waves/CU; in-block LDS ticket balances tiles.
    rast<<<512, 256, 0, stream>>>(verts, faces, zbest);
    pass2<<<B * NPIX / 256, 256, 0, stream>>>(verts, faces, zbest, out);
}

// Round 17
// 36.906 us; speedup vs baseline: 1.1940x; 1.1940x over previous
//
#include <hip/hip_runtime.h>
#include <math.h>

namespace {

constexpr int IMG  = 128;
constexpr int NPIX = IMG * IMG;
constexpr int B    = 4;
constexpr int V    = 600;
constexpr int F    = 1000;
constexpr int FP   = 1024;          // padded face slots (16 chunks x 64)
constexpr float FOCALF = 1.5f;
constexpr float EPSF   = 1e-8f;
// affine-filter margins (error bounds >= 4x slack; rounds 12/15-proven):
constexpr float EW   = 1e-4f;       // |g~ - g_ref| <= ~2.5e-5
constexpr float EBIN = 2e-4f;       // corner-eval slack for bin test
constexpr float DENSAFE = 1e-3f;    // below this -> eps=INF (always exact)

__device__ inline float seg_dist2(float px, float py, float ax, float ay,
                                  float bx, float by) {
#pragma clang fp contract(off)
    float ex = bx - ax, ey = by - ay;
    float dx = px - ax, dy = py - ay;
    float ee = fmaxf(ex * ex + ey * ey, EPSF);
    float t  = (dx * ex + dy * ey) / ee;
    t = fminf(fmaxf(t, 0.0f), 1.0f);
    float rx = dx - t * ex;
    float ry = dy - t * ey;
    return rx * rx + ry * ry;
}

// facedata layout [b][fp][28] (7 x float4, 112B) — identical to round 15:
//  [0-3]:  a0s b0s c0s sden | [4-7]: a1s b1s c1s eps | [8-11]: Zx Zy Zc 0
//  [12-15]: e0x e0y bx by | [16-19]: e1x e1y cx cy | [20-23]: e2x e2y ax ay
//  [24-27]: den az bz cz
// Dead slots (pad/degenerate): c0s=c1s=-1e30 -> never pass the bin test.
__global__ __launch_bounds__(256) void setup(const float* __restrict__ verts,
                                             const int* __restrict__ faces,
                                             float* __restrict__ fdata) {
#pragma clang fp contract(off)
    int t = blockIdx.x * 256 + threadIdx.x;   // grid covers B*FP = 4096
    if (t >= B * FP) return;
    const int b = t >> 10, fp = t & (FP - 1);
    float* o = fdata + (size_t)t * 28;
    bool dead = (fp >= F);
    float ax=0,ay=0,bx=0,by=0,cx=0,cy=0;
    float e0x=0,e0y=0,e1x=0,e1y=0,e2x=0,e2y=0;
    float den=0, z0=0, z1=0, z2=0;
    if (!dead) {
        int i0 = faces[fp * 3 + 0], i1 = faces[fp * 3 + 1], i2 = faces[fp * 3 + 2];
        const float* vb = verts + (size_t)b * V * 3;
        float x0 = vb[i0 * 3], y0 = vb[i0 * 3 + 1]; z0 = vb[i0 * 3 + 2];
        float x1 = vb[i1 * 3], y1 = vb[i1 * 3 + 1]; z1 = vb[i1 * 3 + 2];
        float x2 = vb[i2 * 3], y2 = vb[i2 * 3 + 1]; z2 = vb[i2 * 3 + 2];
        // exact reference projection + edge rounding
        ax = (FOCALF * x0) / z0; ay = (FOCALF * y0) / z0;
        bx = (FOCALF * x1) / z1; by = (FOCALF * y1) / z1;
        cx = (FOCALF * x2) / z2; cy = (FOCALF * y2) / z2;
        e0x = cx - bx; e0y = cy - by;
        e1x = ax - cx; e1y = ay - cy;
        e2x = bx - ax; e2y = by - ay;
        den = e2x * (cy - ay) - e2y * (cx - ax);   // == reference area tree
        if (!(fabsf(den) > EPSF)) { den = 0.0f; dead = true; }
    }
    if (dead) {
        o[0] = 0.0f; o[1] = 0.0f; o[2] = -1e30f; o[3] = 0.0f;
        o[4] = 0.0f; o[5] = 0.0f; o[6] = -1e30f; o[7] = 0.0f;
        #pragma unroll
        for (int k = 8; k < 28; ++k) o[k] = 0.0f;
        return;
    }
    // affine edge coeffs: w_i = a_i*px + b_i*py + c_i
    float a0 = -e0y, b0 = e0x, c0 = e0y * bx - e0x * by;
    float a1 = -e1y, b1 = e1x, c1 = e1y * cx - e1x * cy;
    float a2 = -e2y, b2 = e2x, c2 = e2y * ax - e2x * ay;
    const float s  = den > 0.0f ? 1.0f : -1.0f;
    const float rd = __builtin_amdgcn_rcpf(den);
    const float azr = z0 * rd, bzr = z1 * rd, czr = z2 * rd;
    const float Zx = a0 * azr + a1 * bzr + a2 * czr;
    const float Zy = b0 * azr + b1 * bzr + b2 * czr;
    const float Zc = c0 * azr + c1 * bzr + c2 * czr;
    const float S = (fabsf(a0) + fabsf(b0) + fabsf(c0)) * fabsf(azr)
                  + (fabsf(a1) + fabsf(b1) + fabsf(c1)) * fabsf(bzr)
                  + (fabsf(a2) + fabsf(b2) + fabsf(c2)) * fabsf(czr);
    const float eps = (fabsf(den) < DENSAFE) ? INFINITY : (1e-4f + 2e-6f * S);
    o[0]  = s * a0; o[1]  = s * b0; o[2]  = s * c0; o[3]  = s * den;  // sden=|den|
    o[4]  = s * a1; o[5]  = s * b1; o[6]  = s * c1; o[7]  = eps;
    o[8]  = Zx;     o[9]  = Zy;     o[10] = Zc;     o[11] = 0.0f;
    o[12] = e0x;    o[13] = e0y;    o[14] = bx;     o[15] = by;
    o[16] = e1x;    o[17] = e1y;    o[18] = cx;     o[19] = cy;
    o[20] = e2x;    o[21] = e2y;    o[22] = ax;     o[23] = ay;
    o[24] = den;    o[25] = z0;     o[26] = z1;     o[27] = z2;
}

// Block-owns-tile rasterizer. 1024 blocks (4 img x 256 8x8-tiles, exactly
// 4 blocks/CU) x 512 thr (8 waves). Waves pull the 16 face-chunks off an LDS
// ticket FOR THE SAME TILE and share a live per-pixel bound (tilebest, LDS
// u64 atomicMin, order-free) -> exact-path entries see a warm zbf. A pixel's
// full candidate set resolves in this one block, so the epilogue writes the
// final outputs directly (no zbest, no pass2, no global atomics, no memset).
// Cheap/exact arithmetic is byte-identical to the round-15 kernel.
__global__ __launch_bounds__(512, 8) void rast(const float* __restrict__ fdata,
                                               float* __restrict__ out) {
#pragma clang fp contract(off)
    __shared__ float4 scheap[8][64][3];               // 24 KB
    __shared__ unsigned long long tilebest[64];
    __shared__ unsigned int lticket;
    const int tid  = threadIdx.x;
    const int lane = tid & 63;
    const int w    = tid >> 6;
    const int bk   = blockIdx.x;
    const int b    = bk >> 8;
    const int t    = bk & 255;
    const int ix0  = (t & 15) * 8, iy0 = (t >> 4) * 8;
    if (tid < 64) tilebest[tid] = ~0ULL;
    if (tid == 0) lticket = 0u;
    __syncthreads();

    const int dpx = lane & 7, dpy = lane >> 3;
    const int ix = ix0 + dpx, iy = iy0 + dpy;
    const float px = 1.0f - (2.0f * (float)ix + 1.0f) / (float)IMG;
    const float py = 1.0f - (2.0f * (float)iy + 1.0f) / (float)IMG;
    const float pxmax = 1.0f - (2.0f * (float)ix0 + 1.0f) / (float)IMG;
    const float pxmin = 1.0f - (2.0f * (float)(ix0 + 7) + 1.0f) / (float)IMG;
    const float pymax = 1.0f - (2.0f * (float)iy0 + 1.0f) / (float)IMG;
    const float pymin = 1.0f - (2.0f * (float)(iy0 + 7) + 1.0f) / (float)IMG;

    const volatile unsigned* tb_hi = (const volatile unsigned*)tilebest;

    for (;;) {
        unsigned int c = 0;
        if (lane == 0) c = atomicAdd(&lticket, 1u);
        c = (unsigned int)__shfl((int)c, 0);
        if (c >= 16u) break;
        const int fbase = (int)c * 64;

        // stage this chunk's cheap records into this wave's LDS slot
        const float4* fp4 =
            (const float4*)(fdata + (size_t)(b * FP + fbase + lane) * 28);
        const float4 m0 = fp4[0], m1 = fp4[1], m2 = fp4[2];
        scheap[w][lane][0] = m0;
        scheap[w][lane][1] = m1;
        scheap[w][lane][2] = m2;

        // bin test: max over 8x8 rect of each affine edge >= -EBIN
        const float a2s = -(m0.x + m1.x);
        const float b2s = -(m0.y + m1.y);
        const float c2s = m0.w - m0.z - m1.z;
        bool pass =
            (m0.x * (m0.x >= 0.0f ? pxmax : pxmin)
           + m0.y * (m0.y >= 0.0f ? pymax : pymin) + m0.z) >= -EBIN;
        pass &=
            (m1.x * (m1.x >= 0.0f ? pxmax : pxmin)
           + m1.y * (m1.y >= 0.0f ? pymax : pymin) + m1.z) >= -EBIN;
        pass &=
            (a2s * (a2s >= 0.0f ? pxmax : pxmin)
           + b2s * (b2s >= 0.0f ? pymax : pymin) + c2s) >= -EBIN;

        unsigned long long mask = __ballot(pass);
        while (mask) {
            const int sl = __builtin_ctzll(mask);
            mask &= mask - 1;
            const float4 k0 = scheap[w][sl][0];
            const float4 k1 = scheap[w][sl][1];
            // cheap affine inside test (identical to round 15)
            const float g0 = fmaf(k0.x, px, fmaf(k0.y, py, k0.z));
            const float g1 = fmaf(k1.x, px, fmaf(k1.y, py, k1.z));
            const float g2 = k0.w - g0 - g1;
            const bool maybe = (g0 >= -EW) & (g1 >= -EW) & (g2 >= -EW);
            if (!__any(maybe)) continue;
            const float4 kz = scheap[w][sl][2];
            const float zt = fmaf(kz.x, px, fmaf(kz.y, py, kz.z));
            // live shared bound: hi word of tilebest (monotone, achieved z's)
            const unsigned u = tb_hi[lane * 2 + 1];
            const float zbf = (u == 0xFFFFFFFFu) ? INFINITY : __uint_as_float(u);
            const bool need = maybe & (zt < zbf + k1.w);   // k1.w = eps
            if (__any(need)) {
                // ---- bit-exact reference path (round-15 code) ----
                const float4* fe =
                    (const float4*)(fdata + (size_t)(b * FP + fbase + sl) * 28);
                const float4 r0 = fe[3], r1 = fe[4], r2 = fe[5], r3 = fe[6];
                const float den = r3.x;
                float w0 = r0.x * (py - r0.w) - r0.y * (px - r0.z);
                float w1 = r1.x * (py - r1.w) - r1.y * (px - r1.z);
                float w2 = r2.x * (py - r2.w) - r2.y * (px - r2.z);
                const unsigned ds = __float_as_uint(den) >> 31;
                const bool in0 = (w0 == 0.0f) | ((__float_as_uint(w0) >> 31) == ds);
                const bool in1 = (w1 == 0.0f) | ((__float_as_uint(w1) >> 31) == ds);
                const bool in2 = (w2 == 0.0f) | ((__float_as_uint(w2) >> 31) == ds);
                if (in0 & in1 & in2) {
                    float s0 = w0 / den, s1 = w1 / den, s2 = w2 / den;
                    float z  = s0 * r3.y + s1 * r3.z + s2 * r3.w;
                    if (z > 0.0f) {
                        unsigned long long pk =
                            ((unsigned long long)__float_as_uint(z) << 32) |
                            (unsigned)(fbase + sl);
                        atomicMin(&tilebest[lane], pk);
                    }
                }
            }
        }
    }
    __syncthreads();

    // ---- epilogue: tilebest is FINAL for this tile; write outputs ----
    if (tid < 64) {
        const int eix = ix0 + (tid & 7), eiy = iy0 + (tid >> 3);
        const int gp  = b * NPIX + eiy * IMG + eix;
        const unsigned long long packed = tilebest[tid];
        float o_face = -1.0f, o_z = -1.0f, o_b0 = -1.0f, o_b1 = -1.0f,
              o_b2 = -1.0f, o_d = -1.0f;
        if (packed != ~0ULL) {
            const int   idx = (int)(unsigned)(packed & 0xffffffffu);
            const float z   = __uint_as_float((unsigned)(packed >> 32));
            const float epx = 1.0f - (2.0f * (float)eix + 1.0f) / (float)IMG;
            const float epy = 1.0f - (2.0f * (float)eiy + 1.0f) / (float)IMG;
            const float4* fe =
                (const float4*)(fdata + (size_t)(b * FP + idx) * 28);
            const float4 q0 = fe[3], q1 = fe[4], q2 = fe[5], q3 = fe[6];
            float den = q3.x;
            float w0 = q0.x * (epy - q0.w) - q0.y * (epx - q0.z);
            float w1 = q1.x * (epy - q1.w) - q1.y * (epx - q1.z);
            float w2 = q2.x * (epy - q2.w) - q2.y * (epx - q2.z);
            float s0 = w0 / den, s1 = w1 / den, s2 = w2 / den;
            // a=(q2.z,q2.w) b=(q0.z,q0.w) c=(q1.z,q1.w): ref-rounded coords
            float d2 = fminf(fminf(seg_dist2(epx, epy, q2.z, q2.w, q0.z, q0.w),
                                   seg_dist2(epx, epy, q0.z, q0.w, q1.z, q1.w)),
                             seg_dist2(epx, epy, q1.z, q1.w, q2.z, q2.w));
            o_face = (float)idx; o_z = z;
            o_b0 = s0; o_b1 = s1; o_b2 = s2;
            o_d = -d2;
        }
        out[gp]            = o_face;
        out[B * NPIX + gp] = o_z;
        const int bary_base = 2 * B * NPIX;
        out[bary_base + gp * 3 + 0] = o_b0;
        out[bary_base + gp * 3 + 1] = o_b1;
        out[bary_base + gp * 3 + 2] = o_b2;
        out[5 * B * NPIX + gp] = o_d;
    }
}

} // namespace

extern "C" void kernel_launch(void* const* d_in, const int* in_sizes, int n_in,
                              void* d_out, int out_size, void* d_ws, size_t ws_size,
                              hipStream_t stream) {
    const float* verts = (const float*)d_in[0];  // (B,V,3) f32
    const int*   faces = (const int*)d_in[1];    // (F,3) i32
    float* out = (float*)d_out;

    float* fdata = (float*)d_ws;   // B*FP*112B = 448 KB

    setup<<<B * FP / 256, 256, 0, stream>>>(verts, faces, fdata);
    // 1024 blocks x 8 waves: block = (image, 8x8 tile); 4 blocks/CU exactly;
    // waves pull the 16 face-chunks off an LDS ticket, share live tilebest.
    rast<<<1024, 512, 0, stream>>>(fdata, out);
}

// Round 18
// 32.361 us; speedup vs baseline: 1.3616x; 1.1404x over previous
//
#include <hip/hip_runtime.h>
#include <math.h>

namespace {

constexpr int IMG  = 128;
constexpr int NPIX = IMG * IMG;
constexpr int B    = 4;
constexpr int V    = 600;
constexpr int F    = 1000;
constexpr float FOCALF = 1.5f;
constexpr float EPSF   = 1e-8f;
// affine-filter margins (error bounds >= 4x slack; rounds 12/15-proven):
constexpr float EW   = 1e-4f;       // |g~ - g_ref| <= ~2.5e-5
constexpr float EBIN = 2e-4f;       // corner-eval slack for bin test
constexpr float DENSAFE = 1e-3f;    // below this -> eps=INF (always exact)

struct FaceRec {
    float e0x, e0y, bx, by;
    float e1x, e1y, cx, cy;
    float e2x, e2y, ax, ay;
    float den, z0, z1, z2;
};

// Exact reference projection + edge setup (identical rounding in all users).
__device__ inline FaceRec project_face(const float* __restrict__ vb,
                                       const int* __restrict__ faces, int f) {
#pragma clang fp contract(off)
    FaceRec r;
    int i0 = faces[f * 3 + 0], i1 = faces[f * 3 + 1], i2 = faces[f * 3 + 2];
    float x0 = vb[i0 * 3], y0 = vb[i0 * 3 + 1]; r.z0 = vb[i0 * 3 + 2];
    float x1 = vb[i1 * 3], y1 = vb[i1 * 3 + 1]; r.z1 = vb[i1 * 3 + 2];
    float x2 = vb[i2 * 3], y2 = vb[i2 * 3 + 1]; r.z2 = vb[i2 * 3 + 2];
    r.ax = (FOCALF * x0) / r.z0; r.ay = (FOCALF * y0) / r.z0;
    r.bx = (FOCALF * x1) / r.z1; r.by = (FOCALF * y1) / r.z1;
    r.cx = (FOCALF * x2) / r.z2; r.cy = (FOCALF * y2) / r.z2;
    r.e0x = r.cx - r.bx; r.e0y = r.cy - r.by;
    r.e1x = r.ax - r.cx; r.e1y = r.ay - r.cy;
    r.e2x = r.bx - r.ax; r.e2y = r.by - r.ay;
    float den = r.e2x * (r.cy - r.ay) - r.e2y * (r.cx - r.ax); // == ref area
    if (!(fabsf(den) > EPSF)) den = 0.0f;
    r.den = den;
    return r;
}

__device__ inline float seg_dist2(float px, float py, float ax, float ay,
                                  float bx, float by) {
#pragma clang fp contract(off)
    float ex = bx - ax, ey = by - ay;
    float dx = px - ax, dy = py - ay;
    float ee = fmaxf(ex * ex + ey * ey, EPSF);
    float t  = (dx * ex + dy * ey) / ee;
    t = fminf(fmaxf(t, 0.0f), 1.0f);
    float rx = dx - t * ex;
    float ry = dy - t * ey;
    return rx * rx + ry * ry;
}

// Fused setup+bin+shade — the round-15 kernel with in-block setup.
// 1024 blocks x 512 thr (8 waves). Block = (ch, b, slice): one 64-face chunk
// x 16 tiles (4x4 lattice); waves pull tiles off an LDS ticket.
// tid<64 builds the chunk's 7-float4 records in LDS (same rounding as the
// old setup kernel); scan loop is byte-identical to round 15.
__global__ __launch_bounds__(512, 8) void rast(const float* __restrict__ verts,
                                               const int* __restrict__ faces,
                                               unsigned long long* __restrict__ zbest) {
#pragma clang fp contract(off)
    __shared__ float4 sface[64 * 7];     // 7 KB: this block's chunk
    __shared__ unsigned int lticket;
    const int tid  = threadIdx.x;
    const int lane = tid & 63;
    const int bk   = blockIdx.x;
    const int ch   = bk & 15;          // face chunk
    const int b    = (bk >> 4) & 3;    // image
    const int slice = bk >> 6;         // 0..15 -> 4x4 lattice phase
    if (tid == 0) lticket = 0u;

    // ---- in-block setup: build this chunk's 64 records in LDS ----
    if (tid < 64) {
        const int fid = ch * 64 + tid;
        float4 o0, o1, o2, o3, o4, o5, o6;
        bool dead = (fid >= F);
        FaceRec r = {};
        if (!dead) {
            r = project_face(verts + (size_t)b * V * 3, faces, fid);
            dead = (r.den == 0.0f);
        }
        if (dead) {
            o0 = make_float4(0.0f, 0.0f, -1e30f, 0.0f);
            o1 = make_float4(0.0f, 0.0f, -1e30f, 0.0f);
            o2 = make_float4(0.0f, 0.0f, 0.0f, 0.0f);
            o3 = o4 = o5 = o6 = make_float4(0.0f, 0.0f, 0.0f, 0.0f);
        } else {
            // affine edge coeffs: w_i = a_i*px + b_i*py + c_i
            float a0 = -r.e0y, b0 = r.e0x, c0 = r.e0y * r.bx - r.e0x * r.by;
            float a1 = -r.e1y, b1 = r.e1x, c1 = r.e1y * r.cx - r.e1x * r.cy;
            float a2 = -r.e2y, b2 = r.e2x, c2 = r.e2y * r.ax - r.e2x * r.ay;
            const float s  = r.den > 0.0f ? 1.0f : -1.0f;
            const float rd = __builtin_amdgcn_rcpf(r.den);
            const float azr = r.z0 * rd, bzr = r.z1 * rd, czr = r.z2 * rd;
            const float Zx = a0 * azr + a1 * bzr + a2 * czr;
            const float Zy = b0 * azr + b1 * bzr + b2 * czr;
            const float Zc = c0 * azr + c1 * bzr + c2 * czr;
            const float S = (fabsf(a0) + fabsf(b0) + fabsf(c0)) * fabsf(azr)
                          + (fabsf(a1) + fabsf(b1) + fabsf(c1)) * fabsf(bzr)
                          + (fabsf(a2) + fabsf(b2) + fabsf(c2)) * fabsf(czr);
            const float eps = (fabsf(r.den) < DENSAFE) ? INFINITY
                                                       : (1e-4f + 2e-6f * S);
            o0 = make_float4(s * a0, s * b0, s * c0, s * r.den);  // sden=|den|
            o1 = make_float4(s * a1, s * b1, s * c1, eps);
            o2 = make_float4(Zx, Zy, Zc, 0.0f);
            o3 = make_float4(r.e0x, r.e0y, r.bx, r.by);
            o4 = make_float4(r.e1x, r.e1y, r.cx, r.cy);
            o5 = make_float4(r.e2x, r.e2y, r.ax, r.ay);
            o6 = make_float4(r.den, r.z0, r.z1, r.z2);
        }
        float4* o = &sface[tid * 7];
        o[0] = o0; o[1] = o1; o[2] = o2; o[3] = o3; o[4] = o4; o[5] = o5; o[6] = o6;
    }
    __syncthreads();

    // pin own face's affine coeffs for the bin test (round-15 code)
    const float4 m0 = sface[lane * 7 + 0], m1 = sface[lane * 7 + 1];
    const float a2s = -(m0.x + m1.x);
    const float b2s = -(m0.y + m1.y);
    const float c2s = m0.w - m0.z - m1.z;
    const bool c0x = m0.x >= 0.0f, c0y = m0.y >= 0.0f;
    const bool c1x = m1.x >= 0.0f, c1y = m1.y >= 0.0f;
    const bool c2x = a2s >= 0.0f, c2y = b2s >= 0.0f;

    const int f0 = ch * 64;
    const int dpx = lane & 7, dpy = lane >> 3;

    for (;;) {
        unsigned int j = 0;
        if (lane == 0) j = atomicAdd(&lticket, 1u);
        j = (unsigned int)__shfl((int)j, 0);
        if (j >= 16u) break;
        const unsigned int jj = (j + (unsigned int)ch) & 15u;  // stagger

        const int row = (slice >> 2) + 4 * (int)(jj >> 2);
        const int col = (slice & 3) + 4 * (int)(jj & 3);
        const int ix0 = col * 8, iy0 = row * 8;
        const int ix  = ix0 + dpx, iy = iy0 + dpy;
        const float px = 1.0f - (2.0f * (float)ix + 1.0f) / (float)IMG;
        const float py = 1.0f - (2.0f * (float)iy + 1.0f) / (float)IMG;
        const float pxmax = 1.0f - (2.0f * (float)ix0 + 1.0f) / (float)IMG;
        const float pxmin = 1.0f - (2.0f * (float)(ix0 + 7) + 1.0f) / (float)IMG;
        const float pymax = 1.0f - (2.0f * (float)iy0 + 1.0f) / (float)IMG;
        const float pymin = 1.0f - (2.0f * (float)(iy0 + 7) + 1.0f) / (float)IMG;

        const int gp = b * NPIX + iy * IMG + ix;
        const unsigned ztop = (unsigned)(zbest[gp] >> 32);
        float zbf = (ztop == 0xFFFFFFFFu) ? INFINITY : __uint_as_float(ztop);

        // bin test: max over tile rect of each affine edge >= -EBIN
        bool pass =
            (m0.x * (c0x ? pxmax : pxmin) + m0.y * (c0y ? pymax : pymin) + m0.z)
                >= -EBIN;
        pass &=
            (m1.x * (c1x ? pxmax : pxmin) + m1.y * (c1y ? pymax : pymin) + m1.z)
                >= -EBIN;
        pass &=
            (a2s * (c2x ? pxmax : pxmin) + b2s * (c2y ? pymax : pymin) + c2s)
                >= -EBIN;

        unsigned long long pmin = ~0ULL;
        unsigned long long mask = __ballot(pass);
        while (mask) {
            const int sl = __builtin_ctzll(mask);
            mask &= mask - 1;
            // cheap affine inside test: 2 LDS reads, 6 VALU + 3 cmp
            const float4 k0 = sface[sl * 7 + 0];
            const float4 k1 = sface[sl * 7 + 1];
            const float g0 = fmaf(k0.x, px, fmaf(k0.y, py, k0.z));
            const float g1 = fmaf(k1.x, px, fmaf(k1.y, py, k1.z));
            const float g2 = k0.w - g0 - g1;
            const bool maybe = (g0 >= -EW) & (g1 >= -EW) & (g2 >= -EW);
            if (!__any(maybe)) continue;
            // z~ window (3rd LDS read only when someone might be inside)
            const float4 kz = sface[sl * 7 + 2];
            const float zt = fmaf(kz.x, px, fmaf(kz.y, py, kz.z));
            const bool need = maybe & (zt < zbf + k1.w);   // k1.w = eps (INF->always)
            if (__any(need)) {
                // ---- bit-exact reference path (round-12/15 code) ----
                const float4 r0 = sface[sl * 7 + 3];
                const float4 r1 = sface[sl * 7 + 4];
                const float4 r2 = sface[sl * 7 + 5];
                const float4 r3 = sface[sl * 7 + 6];   // den, az, bz, cz
                const float den = r3.x;
                float w0 = r0.x * (py - r0.w) - r0.y * (px - r0.z);
                float w1 = r1.x * (py - r1.w) - r1.y * (px - r1.z);
                float w2 = r2.x * (py - r2.w) - r2.y * (px - r2.z);
                const unsigned ds = __float_as_uint(den) >> 31;
                const bool in0 = (w0 == 0.0f) | ((__float_as_uint(w0) >> 31) == ds);
                const bool in1 = (w1 == 0.0f) | ((__float_as_uint(w1) >> 31) == ds);
                const bool in2 = (w2 == 0.0f) | ((__float_as_uint(w2) >> 31) == ds);
                if (in0 & in1 & in2) {
                    float s0 = w0 / den, s1 = w1 / den, s2 = w2 / den;
                    float z  = s0 * r3.y + s1 * r3.z + s2 * r3.w;
                    if (z > 0.0f) {
                        unsigned long long pk =
                            ((unsigned long long)__float_as_uint(z) << 32) |
                            (unsigned)(f0 + sl);
                        pmin = pmin < pk ? pmin : pk;
                        zbf  = fminf(zbf, z);
                    }
                }
            }
        }
        if (pmin != ~0ULL) atomicMin(&zbest[gp], pmin);
    }
}

// Unpack winner; recompute bary + dists from verts/faces with the exact
// reference formulas (bit-identical — proven in round 16's passing run).
__global__ __launch_bounds__(256) void pass2(const float* __restrict__ verts,
                                             const int* __restrict__ faces,
                                             const unsigned long long* __restrict__ zbest,
                                             float* __restrict__ out) {
#pragma clang fp contract(off)
    const int gp = blockIdx.x * 256 + threadIdx.x;
    const int b  = gp >> 14;
    const int p  = gp & (NPIX - 1);
    const int ix = p & (IMG - 1), iy = p >> 7;

    unsigned long long packed = zbest[gp];
    float o_face = -1.0f, o_z = -1.0f, o_b0 = -1.0f, o_b1 = -1.0f,
          o_b2 = -1.0f, o_d = -1.0f;

    if (packed != ~0ULL) {
        const int   idx = (int)(unsigned)(packed & 0xffffffffu);
        const float z   = __uint_as_float((unsigned)(packed >> 32));
        const float px  = 1.0f - (2.0f * (float)ix + 1.0f) / (float)IMG;
        const float py  = 1.0f - (2.0f * (float)iy + 1.0f) / (float)IMG;

        FaceRec r = project_face(verts + (size_t)b * V * 3, faces, idx);
        float w0 = r.e0x * (py - r.by) - r.e0y * (px - r.bx);
        float w1 = r.e1x * (py - r.cy) - r.e1y * (px - r.cx);
        float w2 = r.e2x * (py - r.ay) - r.e2y * (px - r.ax);
        float s0 = w0 / r.den, s1 = w1 / r.den, s2 = w2 / r.den;

        float d2 = fminf(fminf(seg_dist2(px, py, r.ax, r.ay, r.bx, r.by),
                               seg_dist2(px, py, r.bx, r.by, r.cx, r.cy)),
                         seg_dist2(px, py, r.cx, r.cy, r.ax, r.ay));
        o_face = (float)idx; o_z = z;
        o_b0 = s0; o_b1 = s1; o_b2 = s2;
        o_d = -d2;
    }

    out[gp]            = o_face;
    out[B * NPIX + gp] = o_z;
    const int bary_base = 2 * B * NPIX;
    out[bary_base + gp * 3 + 0] = o_b0;
    out[bary_base + gp * 3 + 1] = o_b1;
    out[bary_base + gp * 3 + 2] = o_b2;
    out[5 * B * NPIX + gp] = o_d;
}

} // namespace

extern "C" void kernel_launch(void* const* d_in, const int* in_sizes, int n_in,
                              void* d_out, int out_size, void* d_ws, size_t ws_size,
                              hipStream_t stream) {
    const float* verts = (const float*)d_in[0];  // (B,V,3) f32
    const int*   faces = (const int*)d_in[1];    // (F,3) i32
    float* out = (float*)d_out;

    unsigned long long* zbest = (unsigned long long*)d_ws;   // 512 KB

    hipMemsetAsync(zbest, 0xFF, (size_t)B * NPIX * 8, stream);
    // 1024 blocks x 8 waves, 4 blocks/CU; block = (chunk, image, slice);
    // 16 tiles via LDS ticket; in-block setup replaces the setup kernel.
    rast<<<1024, 512, 0, stream>>>(verts, faces, zbest);
    pass2<<<B * NPIX / 256, 256, 0, stream>>>(verts, faces, zbest, out);
}

// Round 19
// 31.486 us; speedup vs baseline: 1.3995x; 1.0278x over previous
//
#include <hip/hip_runtime.h>
#include <math.h>

namespace {

constexpr int IMG  = 128;
constexpr int NPIX = IMG * IMG;
constexpr int B    = 4;
constexpr int V    = 600;
constexpr int F    = 1000;
constexpr int FP   = 1024;          // padded face slots (16 chunks x 64)
constexpr float FOCALF = 1.5f;
constexpr float EPSF   = 1e-8f;
// affine-filter margins (error bounds >= 4x slack; rounds 12/15-proven):
constexpr float EW   = 1e-4f;       // |g~ - g_ref| <= ~2.5e-5
constexpr float EBIN = 2e-4f;       // corner-eval slack for bin test
constexpr float DENSAFE = 1e-3f;    // below this -> eps=INF (always exact)

__device__ inline float seg_dist2(float px, float py, float ax, float ay,
                                  float bx, float by) {
#pragma clang fp contract(off)
    float ex = bx - ax, ey = by - ay;
    float dx = px - ax, dy = py - ay;
    float ee = fmaxf(ex * ex + ey * ey, EPSF);
    float t  = (dx * ex + dy * ey) / ee;
    t = fminf(fmaxf(t, 0.0f), 1.0f);
    float rx = dx - t * ex;
    float ry = dy - t * ey;
    return rx * rx + ry * ry;
}

// facedata layout [b][fp][28] (7 x float4, 112B):
//  [0-3]:  a0s b0s c0s sden   (sign-folded edge-0 affine coeffs; sden=|den|)
//  [4-7]:  a1s b1s c1s eps    (edge-1; eps = z-window margin, INF for slivers)
//  [8-11]: Zx  Zy  Zc  0      (affine z~ coeffs, rcp(den)-folded)
//  [12-15]: e0x e0y bx by  | [16-19]: e1x e1y cx cy | [20-23]: e2x e2y ax ay
//  [24-27]: den az bz cz      (exact-path data, reference-rounded)
// Dead slots (pad/degenerate): c0s=-1e30 -> never passes bin or cheap test.
__global__ __launch_bounds__(256) void setup_clear(const float* __restrict__ verts,
                                                   const int* __restrict__ faces,
                                                   float* __restrict__ fdata,
                                                   unsigned long long* __restrict__ zbest) {
#pragma clang fp contract(off)
    int t = blockIdx.x * 256 + threadIdx.x;   // grid covers B*NPIX = 65536
    zbest[t] = ~0ULL;
    if (t >= B * FP) return;
    const int b = t >> 10, fp = t & (FP - 1);
    float* o = fdata + (size_t)t * 28;
    bool dead = (fp >= F);
    float ax=0,ay=0,bx=0,by=0,cx=0,cy=0;
    float e0x=0,e0y=0,e1x=0,e1y=0,e2x=0,e2y=0;
    float den=0, z0=0, z1=0, z2=0;
    if (!dead) {
        int i0 = faces[fp * 3 + 0], i1 = faces[fp * 3 + 1], i2 = faces[fp * 3 + 2];
        const float* vb = verts + (size_t)b * V * 3;
        float x0 = vb[i0 * 3], y0 = vb[i0 * 3 + 1]; z0 = vb[i0 * 3 + 2];
        float x1 = vb[i1 * 3], y1 = vb[i1 * 3 + 1]; z1 = vb[i1 * 3 + 2];
        float x2 = vb[i2 * 3], y2 = vb[i2 * 3 + 1]; z2 = vb[i2 * 3 + 2];
        // exact reference projection + edge rounding
        ax = (FOCALF * x0) / z0; ay = (FOCALF * y0) / z0;
        bx = (FOCALF * x1) / z1; by = (FOCALF * y1) / z1;
        cx = (FOCALF * x2) / z2; cy = (FOCALF * y2) / z2;
        e0x = cx - bx; e0y = cy - by;
        e1x = ax - cx; e1y = ay - cy;
        e2x = bx - ax; e2y = by - ay;
        den = e2x * (cy - ay) - e2y * (cx - ax);   // == reference area tree
        if (!(fabsf(den) > EPSF)) { den = 0.0f; dead = true; }
    }
    if (dead) {
        o[0] = 0.0f; o[1] = 0.0f; o[2] = -1e30f; o[3] = 0.0f;
        #pragma unroll
        for (int k = 4; k < 28; ++k) o[k] = 0.0f;
        return;
    }
    // affine edge coeffs: w_i = a_i*px + b_i*py + c_i
    float a0 = -e0y, b0 = e0x, c0 = e0y * bx - e0x * by;
    float a1 = -e1y, b1 = e1x, c1 = e1y * cx - e1x * cy;
    float a2 = -e2y, b2 = e2x, c2 = e2y * ax - e2x * ay;
    const float s  = den > 0.0f ? 1.0f : -1.0f;
    const float rd = __builtin_amdgcn_rcpf(den);
    const float azr = z0 * rd, bzr = z1 * rd, czr = z2 * rd;
    const float Zx = a0 * azr + a1 * bzr + a2 * czr;
    const float Zy = b0 * azr + b1 * bzr + b2 * czr;
    const float Zc = c0 * azr + c1 * bzr + c2 * czr;
    // abs-sum for the z~ error bound (cancellation-safe)
    const float S = (fabsf(a0) + fabsf(b0) + fabsf(c0)) * fabsf(azr)
                  + (fabsf(a1) + fabsf(b1) + fabsf(c1)) * fabsf(bzr)
                  + (fabsf(a2) + fabsf(b2) + fabsf(c2)) * fabsf(czr);
    const float eps = (fabsf(den) < DENSAFE) ? INFINITY : (1e-4f + 2e-6f * S);
    o[0]  = s * a0; o[1]  = s * b0; o[2]  = s * c0; o[3]  = s * den;  // sden=|den|
    o[4]  = s * a1; o[5]  = s * b1; o[6]  = s * c1; o[7]  = eps;
    o[8]  = Zx;     o[9]  = Zy;     o[10] = Zc;     o[11] = 0.0f;
    o[12] = e0x;    o[13] = e0y;    o[14] = bx;     o[15] = by;
    o[16] = e1x;    o[17] = e1y;    o[18] = cx;     o[19] = cy;
    o[20] = e2x;    o[21] = e2y;    o[22] = ax;     o[23] = ay;
    o[24] = den;    o[25] = z0;     o[26] = z1;     o[27] = z2;
}

// Fused bin+shade. 1024 blocks x 512 thr (8 waves). Block = (ch, b, slice):
// one 64-face chunk x 16 tiles (4x4 lattice); waves pull tiles off an LDS
// ticket. Bin test from per-lane pinned affine coeffs. Survivor loop: 2 LDS
// float4 -> affine g0,g1 + identity g2 (=|den|-g0-g1); z~ window from a 3rd
// float4 only when maybe-inside. Exact reference path (bit-identical to the
// passing round-12 kernel) only when some lane might improve its bound.
__global__ __launch_bounds__(512, 8) void rast(const float* __restrict__ fdata,
                                               unsigned long long* __restrict__ zbest) {
#pragma clang fp contract(off)
    __shared__ float4 sface[64 * 7];     // 7 KB: this block's chunk
    __shared__ unsigned int lticket;
    const int tid  = threadIdx.x;
    const int lane = tid & 63;
    const int bk   = blockIdx.x;
    const int ch   = bk & 15;          // face chunk
    const int b    = (bk >> 4) & 3;    // image
    const int slice = bk >> 6;         // 0..15 -> 4x4 lattice phase
    if (tid == 0) lticket = 0u;

    const int f0 = ch * 64;
    // flat cooperative stage: chunk is 448 contiguous float4s
    const float4* gflat = (const float4*)(fdata + (size_t)(b * FP + f0) * 28);
    if (tid < 448) ((float4*)sface)[tid] = gflat[tid];

    // pin own face's affine coeffs for the bin test
    const float4* fd4 = (const float4*)(fdata + (size_t)(b * FP + f0 + lane) * 28);
    const float4 m0 = fd4[0], m1 = fd4[1];
    // edge 2 via identity: a2s=-(a0s+a1s), b2s=-(b0s+b1s), c2s=sden-c0s-c1s
    const float a2s = -(m0.x + m1.x);
    const float b2s = -(m0.y + m1.y);
    const float c2s = m0.w - m0.z - m1.z;
    const bool c0x = m0.x >= 0.0f, c0y = m0.y >= 0.0f;
    const bool c1x = m1.x >= 0.0f, c1y = m1.y >= 0.0f;
    const bool c2x = a2s >= 0.0f, c2y = b2s >= 0.0f;
    __syncthreads();

    const int dpx = lane & 7, dpy = lane >> 3;

    for (;;) {
        unsigned int j = 0;
        if (lane == 0) j = atomicAdd(&lticket, 1u);
        j = (unsigned int)__shfl((int)j, 0);
        if (j >= 16u) break;
        const unsigned int jj = (j + (unsigned int)ch) & 15u;  // stagger

        const int row = (slice >> 2) + 4 * (int)(jj >> 2);
        const int col = (slice & 3) + 4 * (int)(jj & 3);
        const int ix0 = col * 8, iy0 = row * 8;
        const int ix  = ix0 + dpx, iy = iy0 + dpy;
        const float px = 1.0f - (2.0f * (float)ix + 1.0f) / (float)IMG;
        const float py = 1.0f - (2.0f * (float)iy + 1.0f) / (float)IMG;
        const float pxmax = 1.0f - (2.0f * (float)ix0 + 1.0f) / (float)IMG;
        const float pxmin = 1.0f - (2.0f * (float)(ix0 + 7) + 1.0f) / (float)IMG;
        const float pymax = 1.0f - (2.0f * (float)iy0 + 1.0f) / (float)IMG;
        const float pymin = 1.0f - (2.0f * (float)(iy0 + 7) + 1.0f) / (float)IMG;

        const int gp = b * NPIX + iy * IMG + ix;
        const unsigned ztop = (unsigned)(zbest[gp] >> 32);
        float zbf = (ztop == 0xFFFFFFFFu) ? INFINITY : __uint_as_float(ztop);

        // bin test: max over tile rect of each affine edge >= -EBIN
        bool pass =
            (m0.x * (c0x ? pxmax : pxmin) + m0.y * (c0y ? pymax : pymin) + m0.z)
                >= -EBIN;
        pass &=
            (m1.x * (c1x ? pxmax : pxmin) + m1.y * (c1y ? pymax : pymin) + m1.z)
                >= -EBIN;
        pass &=
            (a2s * (c2x ? pxmax : pxmin) + b2s * (c2y ? pymax : pymin) + c2s)
                >= -EBIN;

        unsigned long long pmin = ~0ULL;
        unsigned long long mask = __ballot(pass);
        while (mask) {
            const int sl = __builtin_ctzll(mask);
            mask &= mask - 1;
            // cheap affine inside test: 2 LDS reads, 6 VALU + 3 cmp
            const float4 k0 = sface[sl * 7 + 0];
            const float4 k1 = sface[sl * 7 + 1];
            const float g0 = fmaf(k0.x, px, fmaf(k0.y, py, k0.z));
            const float g1 = fmaf(k1.x, px, fmaf(k1.y, py, k1.z));
            const float g2 = k0.w - g0 - g1;
            const bool maybe = (g0 >= -EW) & (g1 >= -EW) & (g2 >= -EW);
            if (!__any(maybe)) continue;
            // z~ window (3rd LDS read only when someone might be inside)
            const float4 kz = sface[sl * 7 + 2];
            const float zt = fmaf(kz.x, px, fmaf(kz.y, py, kz.z));
            const bool need = maybe & (zt < zbf + k1.w);   // k1.w = eps (INF->always)
            if (__any(need)) {
                // ---- bit-exact reference path (round-12 code) ----
                const float4 r0 = sface[sl * 7 + 3];
                const float4 r1 = sface[sl * 7 + 4];
                const float4 r2 = sface[sl * 7 + 5];
                const float4 r3 = sface[sl * 7 + 6];   // den, az, bz, cz
                const float den = r3.x;
                float w0 = r0.x * (py - r0.w) - r0.y * (px - r0.z);
                float w1 = r1.x * (py - r1.w) - r1.y * (px - r1.z);
                float w2 = r2.x * (py - r2.w) - r2.y * (px - r2.z);
                const unsigned ds = __float_as_uint(den) >> 31;
                const bool in0 = (w0 == 0.0f) | ((__float_as_uint(w0) >> 31) == ds);
                const bool in1 = (w1 == 0.0f) | ((__float_as_uint(w1) >> 31) == ds);
                const bool in2 = (w2 == 0.0f) | ((__float_as_uint(w2) >> 31) == ds);
                if (in0 & in1 & in2) {
                    float s0 = w0 / den, s1 = w1 / den, s2 = w2 / den;
                    float z  = s0 * r3.y + s1 * r3.z + s2 * r3.w;
                    if (z > 0.0f) {
                        unsigned long long pk =
                            ((unsigned long long)__float_as_uint(z) << 32) |
                            (unsigned)(f0 + sl);
                        pmin = pmin < pk ? pmin : pk;
                        zbf  = fminf(zbf, z);
                    }
                }
            }
        }
        if (pmin != ~0ULL) atomicMin(&zbest[gp], pmin);
    }
}

// Unpack winner; recompute bary + dists from fdata (reference-rounded values).
__global__ __launch_bounds__(256) void pass2(const float* __restrict__ fdata,
                                             const unsigned long long* __restrict__ zbest,
                                             float* __restrict__ out) {
#pragma clang fp contract(off)
    const int gp = blockIdx.x * 256 + threadIdx.x;
    const int b  = gp >> 14;
    const int p  = gp & (NPIX - 1);
    const int ix = p & (IMG - 1), iy = p >> 7;

    unsigned long long packed = zbest[gp];
    float o_face = -1.0f, o_z = -1.0f, o_b0 = -1.0f, o_b1 = -1.0f,
          o_b2 = -1.0f, o_d = -1.0f;

    if (packed != ~0ULL) {
        const int   idx = (int)(unsigned)(packed & 0xffffffffu);  // face id (==slot)
        const float z   = __uint_as_float((unsigned)(packed >> 32));
        const float px  = 1.0f - (2.0f * (float)ix + 1.0f) / (float)IMG;
        const float py  = 1.0f - (2.0f * (float)iy + 1.0f) / (float)IMG;

        const float4* fd4 = (const float4*)(fdata + (size_t)(b * FP + idx) * 28);
        float4 q0 = fd4[3], q1 = fd4[4], q2 = fd4[5], q3 = fd4[6];
        float den = q3.x;
        float w0 = q0.x * (py - q0.w) - q0.y * (px - q0.z);
        float w1 = q1.x * (py - q1.w) - q1.y * (px - q1.z);
        float w2 = q2.x * (py - q2.w) - q2.y * (px - q2.z);
        float s0 = w0 / den, s1 = w1 / den, s2 = w2 / den;

        // a=(q2.z,q2.w)  b=(q0.z,q0.w)  c=(q1.z,q1.w): reference-rounded coords
        float d2 = fminf(fminf(seg_dist2(px, py, q2.z, q2.w, q0.z, q0.w),
                               seg_dist2(px, py, q0.z, q0.w, q1.z, q1.w)),
                         seg_dist2(px, py, q1.z, q1.w, q2.z, q2.w));
        o_face = (float)idx; o_z = z;
        o_b0 = s0; o_b1 = s1; o_b2 = s2;
        o_d = -d2;
    }

    out[gp]            = o_face;
    out[B * NPIX + gp] = o_z;
    const int bary_base = 2 * B * NPIX;
    out[bary_base + gp * 3 + 0] = o_b0;
    out[bary_base + gp * 3 + 1] = o_b1;
    out[bary_base + gp * 3 + 2] = o_b2;
    out[5 * B * NPIX + gp] = o_d;
}

} // namespace

extern "C" void kernel_launch(void* const* d_in, const int* in_sizes, int n_in,
                              void* d_out, int out_size, void* d_ws, size_t ws_size,
                              hipStream_t stream) {
    const float* verts = (const float*)d_in[0];  // (B,V,3) f32
    const int*   faces = (const int*)d_in[1];    // (F,3) i32
    float* out = (float*)d_out;

    // ws layout: zbest 512KB | fdata B*FP*112B = 448KB
    char* ws = (char*)d_ws;
    unsigned long long* zbest = (unsigned long long*)ws;
    float* fdata = (float*)(ws + (size_t)B * NPIX * 8);

    setup_clear<<<B * NPIX / 256, 256, 0, stream>>>(verts, faces, fdata, zbest);
    // 1024 blocks x 8 waves = 8192 waves, all co-resident (32 waves/CU);
    // block = (chunk, image, lattice-slice), 16 tiles via LDS ticket.
    rast<<<1024, 512, 0, stream>>>(fdata, zbest);
    pass2<<<B * NPIX / 256, 256, 0, stream>>>(fdata, zbest, out);
}